// Round 1
// baseline (1165.675 us; speedup 1.0000x reference)
//
#include <hip/hip_runtime.h>
#include <hip/hip_bf16.h>
#include <math.h>

// Problem constants (fixed by the reference setup)
#define XT    1000000   // items
#define DQ    128       // dims
#define BQ    256       // queries
#define BX    128       // items per K1 block
#define KB    32        // k-chunk staged per LDS pass
#define CHUNK 16        // items per max-chunk
#define NCH   62500     // XT / CHUNK
#define CAP   128       // max chunks rescored per query
#define SELBUF 2048
#define NCAND (CAP * CHUNK)  // 2048 candidates per query
#define KTOP  100
#define DELTA 0.05f     // safety margin on chunk-max threshold

// ---- order-preserving float<->uint packing: (score desc, id asc) as one u64 ----
__device__ __forceinline__ unsigned ordf(float f) {
  unsigned u = __float_as_uint(f);
  return (u & 0x80000000u) ? ~u : (u ^ 0x80000000u);
}
__device__ __forceinline__ float unordf(unsigned k) {
  unsigned bits = (k & 0x80000000u) ? (k ^ 0x80000000u) : ~k;
  return __uint_as_float(bits);
}
__device__ __forceinline__ unsigned long long packkv(float v, unsigned id) {
  return ((unsigned long long)ordf(v) << 32) | (unsigned long long)(~id);
}
__device__ __forceinline__ float pk_val(unsigned long long e) { return unordf((unsigned)(e >> 32)); }
__device__ __forceinline__ unsigned pk_id(unsigned long long e) { return ~(unsigned)(e & 0xFFFFFFFFu); }

// ---- in-LDS bitonic sort, ascending, N power of two ----
template <int N>
__device__ void bitonic_sort(unsigned long long* buf) {
  for (int k = 2; k <= N; k <<= 1) {
    for (int j = k >> 1; j > 0; j >>= 1) {
      for (int e = threadIdx.x; e < N; e += blockDim.x) {
        int p = e ^ j;
        if (p > e) {
          unsigned long long a = buf[e], b = buf[p];
          bool up = ((e & k) == 0);
          if (up ? (a > b) : (a < b)) { buf[e] = b; buf[p] = a; }
        }
      }
      __syncthreads();
    }
  }
}

// =================== K1: fp32 GEMM + per-16-item-chunk max ===================
// Block: 512 threads. Tile: 256 q x 128 items. Each thread: 8q x 8x accumulators.
// Accumulation: single fmaf chain over d ascending (matches BLAS microkernel rounding).
__global__ __launch_bounds__(512) void k1_gemm_max(
    const float* __restrict__ Q, const float* __restrict__ It, float* __restrict__ M) {
  __shared__ float Qs[KB][260];  // [d][q], pad 260 keeps float4 alignment, conflict-light
  __shared__ float Xs[KB][132];  // [d][x]
  const int t = threadIdx.x;
  const int x0 = blockIdx.x * BX;
  const int tx = t & 15;   // item group
  const int ty = t >> 4;   // query group (0..31)

  float acc[8][8];
#pragma unroll
  for (int i = 0; i < 8; ++i)
#pragma unroll
    for (int j = 0; j < 8; ++j) acc[i][j] = 0.f;

  for (int kb = 0; kb < DQ / KB; ++kb) {
    {  // stage Q (256 x 32) transposed -> Qs[d][q]
      const int sub = t & 7, ql = t >> 3;
#pragma unroll
      for (int p = 0; p < 4; ++p) {
        int q = ql + p * 64;
        float4 v = *(const float4*)&Q[q * DQ + kb * KB + sub * 4];
        Qs[sub * 4 + 0][q] = v.x;
        Qs[sub * 4 + 1][q] = v.y;
        Qs[sub * 4 + 2][q] = v.z;
        Qs[sub * 4 + 3][q] = v.w;
      }
    }
    {  // stage X (32 x 128) -> Xs[d][x], zero-fill past end of corpus
      const int xs = t & 31, dl = t >> 5;
#pragma unroll
      for (int p = 0; p < 2; ++p) {
        int d = dl + p * 16;
        int x = x0 + xs * 4;
        float4 v;
        if (x + 3 < XT) v = *(const float4*)&It[(size_t)(kb * KB + d) * XT + x];
        else v = make_float4(0.f, 0.f, 0.f, 0.f);
        *(float4*)&Xs[d][xs * 4] = v;
      }
    }
    __syncthreads();
#pragma unroll 4
    for (int d = 0; d < KB; ++d) {
      float4 qa = *(const float4*)&Qs[d][ty * 8];
      float4 qb = *(const float4*)&Qs[d][ty * 8 + 4];
      float4 xa = *(const float4*)&Xs[d][tx * 4];
      float4 xb = *(const float4*)&Xs[d][tx * 4 + 64];
      float qr[8] = {qa.x, qa.y, qa.z, qa.w, qb.x, qb.y, qb.z, qb.w};
      float xr[8] = {xa.x, xa.y, xa.z, xa.w, xb.x, xb.y, xb.z, xb.w};
#pragma unroll
      for (int i = 0; i < 8; ++i)
#pragma unroll
        for (int j = 0; j < 8; ++j)
          acc[i][j] = fmaf(qr[i], xr[j], acc[i][j]);
    }
    __syncthreads();
  }

  // Epilogue: per-(q, 16-item-chunk) max. Thread's x: {tx*4..+3} and {64+tx*4..+3}.
  float* Ms = &Qs[0][0];  // reuse LDS as [8][257]: idx c*257+q
#pragma unroll
  for (int i = 0; i < 8; ++i) {
    float ma = fmaxf(fmaxf(acc[i][0], acc[i][1]), fmaxf(acc[i][2], acc[i][3]));
    float mb = fmaxf(fmaxf(acc[i][4], acc[i][5]), fmaxf(acc[i][6], acc[i][7]));
    ma = fmaxf(ma, __shfl_xor(ma, 1));
    ma = fmaxf(ma, __shfl_xor(ma, 2));
    mb = fmaxf(mb, __shfl_xor(mb, 1));
    mb = fmaxf(mb, __shfl_xor(mb, 2));
    if ((tx & 3) == 0) {
      int q = ty * 8 + i;
      int ca = tx >> 2;
      Ms[ca * 257 + q] = ma;
      Ms[(ca + 4) * 257 + q] = mb;
    }
  }
  __syncthreads();
  {  // coalesced-ish write: thread -> (q = t>>1, half = t&1) float4 of 4 maxima
    int q = t >> 1, half = t & 1;
    int cbase = blockIdx.x * 8 + half * 4;
    if (cbase + 3 < NCH) {
      float4 v;
      v.x = Ms[(half * 4 + 0) * 257 + q];
      v.y = Ms[(half * 4 + 1) * 257 + q];
      v.z = Ms[(half * 4 + 2) * 257 + q];
      v.w = Ms[(half * 4 + 3) * 257 + q];
      *(float4*)&M[(size_t)q * NCH + cbase] = v;
    }
  }
}

// =================== K2: per-query exact top-100 of chunk maxima ===================
// Streaming threshold+buffer selection; emits <=CAP chunk ids with max >= tau-DELTA.
__global__ __launch_bounds__(256) void k2_select(
    const float* __restrict__ M, int* __restrict__ list, int* __restrict__ cnt_out) {
  const int q = blockIdx.x;
  const float4* Mq = (const float4*)(M + (size_t)q * NCH);
  __shared__ unsigned long long buf[SELBUF];
  __shared__ int cnt;
  __shared__ float thr;
  __shared__ int scratch;
  if (threadIdx.x == 0) { cnt = 0; thr = -3.0e38f; }
  __syncthreads();
  const int NF4 = NCH / 4;  // 15625
  for (int base = 0; base < NF4; base += blockDim.x) {
    const int idx = base + threadIdx.x;
    const float t = thr - DELTA;
    if (idx < NF4) {
      float4 v = Mq[idx];
      float vals[4] = {v.x, v.y, v.z, v.w};
#pragma unroll
      for (int j = 0; j < 4; ++j) {
        if (vals[j] >= t) {
          int p = atomicAdd(&cnt, 1);
          if (p < SELBUF) buf[p] = packkv(vals[j], (unsigned)(idx * 4 + j));
        }
      }
    }
    __syncthreads();
    if (cnt > 1024) {  // compact: keep everything within DELTA of the running 100th
      for (int s = cnt + threadIdx.x; s < SELBUF; s += blockDim.x) buf[s] = 0ULL;
      __syncthreads();
      bitonic_sort<SELBUF>(buf);
      float newThr = pk_val(buf[SELBUF - KTOP]);
      if (threadIdx.x == 0) scratch = 0;
      __syncthreads();
      for (int s = threadIdx.x; s < SELBUF; s += blockDim.x)
        if (buf[s] != 0ULL && pk_val(buf[s]) >= newThr - DELTA) atomicAdd(&scratch, 1);
      __syncthreads();
      int keep = scratch;
      if (keep > 1024) keep = 1024;
      for (int s = threadIdx.x; s < keep; s += blockDim.x) buf[s] = buf[SELBUF - keep + s];
      __syncthreads();
      if (threadIdx.x == 0) { cnt = keep; thr = newThr; }
      __syncthreads();
    }
  }
  // final selection + emission
  for (int s = cnt + threadIdx.x; s < SELBUF; s += blockDim.x) buf[s] = 0ULL;
  __syncthreads();
  bitonic_sort<SELBUF>(buf);
  float tau = pk_val(buf[SELBUF - KTOP]);
  if (threadIdx.x == 0) scratch = 0;
  __syncthreads();
  for (int r = threadIdx.x; r < CAP; r += blockDim.x) {
    unsigned long long e = buf[SELBUF - 1 - r];
    if (e != 0ULL && pk_val(e) >= tau - DELTA) {
      list[q * CAP + r] = (int)pk_id(e);
      atomicAdd(&scratch, 1);
    }
  }
  __syncthreads();
  if (threadIdx.x == 0) cnt_out[q] = scratch;
}

// =================== K3: exact fp32 rescore of listed chunks ===================
__global__ __launch_bounds__(256) void k3_rescore(
    const float* __restrict__ Q, const float* __restrict__ It,
    const int* __restrict__ list, const int* __restrict__ cnt_in,
    unsigned long long* __restrict__ cand) {
  const int q = blockIdx.x >> 3;
  const int sg = blockIdx.x & 7;
  __shared__ float qv[DQ];
  if (threadIdx.x < DQ) qv[threadIdx.x] = Q[q * DQ + threadIdx.x];
  __syncthreads();
  const int s = threadIdx.x >> 4;
  const int it = threadIdx.x & 15;
  const int gs = sg * 16 + s;
  unsigned long long out = 0ULL;
  if (gs < cnt_in[q]) {
    const int chunk = list[q * CAP + gs];
    const int x = chunk * CHUNK + it;
    float a = 0.f;
#pragma unroll 8
    for (int d = 0; d < DQ; ++d) a = fmaf(qv[d], It[(size_t)d * XT + x], a);
    out = packkv(a, (unsigned)x);
  }
  cand[(size_t)q * NCAND + gs * CHUNK + it] = out;
}

// =================== K4: final per-query top-100 ===================
__global__ __launch_bounds__(256) void k4_final(
    const unsigned long long* __restrict__ cand, float* __restrict__ out) {
  const int q = blockIdx.x;
  __shared__ unsigned long long buf[NCAND];
  for (int s = threadIdx.x; s < NCAND; s += blockDim.x) buf[s] = cand[(size_t)q * NCAND + s];
  __syncthreads();
  bitonic_sort<NCAND>(buf);
  for (int r = threadIdx.x; r < KTOP; r += blockDim.x) {
    unsigned long long e = buf[NCAND - 1 - r];
    out[q * KTOP + r] = pk_val(e);                          // topk_logits
    out[BQ * KTOP + q * KTOP + r] = (float)pk_id(e);        // topk_item_ids (ids = arange)
  }
}

extern "C" void kernel_launch(void* const* d_in, const int* in_sizes, int n_in,
                              void* d_out, int out_size, void* d_ws, size_t ws_size,
                              hipStream_t stream) {
  const float* Q = (const float*)d_in[0];   // [256,128]
  const float* It = (const float*)d_in[1];  // [128,1000000]
  float* out = (float*)d_out;               // [25600 logits][25600 ids]
  char* ws = (char*)d_ws;
  // ws layout: M (64,000,000 B) | cand (4,194,304 B) | list (131,072 B) | cnt (1,024 B)
  float* M = (float*)ws;
  unsigned long long* cand = (unsigned long long*)(ws + (size_t)64000000);
  int* list = (int*)(ws + (size_t)64000000 + 4194304);
  int* cnt = (int*)(ws + (size_t)64000000 + 4194304 + 131072);

  k1_gemm_max<<<dim3((XT + BX - 1) / BX), dim3(512), 0, stream>>>(Q, It, M);
  k2_select<<<dim3(BQ), dim3(256), 0, stream>>>(M, list, cnt);
  k3_rescore<<<dim3(BQ * 8), dim3(256), 0, stream>>>(Q, It, list, cnt, cand);
  k4_final<<<dim3(BQ), dim3(256), 0, stream>>>(cand, out);
}

// Round 2
// 796.225 us; speedup vs baseline: 1.4640x; 1.4640x over previous
//
#include <hip/hip_runtime.h>
#include <hip/hip_bf16.h>
#include <math.h>

// Problem constants (fixed by the reference setup)
#define XT    1000000   // items
#define DQ    128       // dims
#define BQ    256       // queries
#define TI    128       // items per K1 block
#define CHUNK 16        // items per max-chunk
#define NCH   62500     // XT / CHUNK
#define CAP   256       // max chunks rescored per query
#define SELBUF 2048
#define NCAND (CAP * CHUNK)  // 4096 candidates per query
#define KTOP  100
#define DELTA 0.5f      // covers 2x worst bf16 filter error (~0.13) with margin

typedef float f32x4 __attribute__((ext_vector_type(4)));
typedef short bf16x8 __attribute__((ext_vector_type(8)));

// ---- order-preserving float<->uint packing: (score desc, id asc) as one u64 ----
__device__ __forceinline__ unsigned ordf(float f) {
  unsigned u = __float_as_uint(f);
  return (u & 0x80000000u) ? ~u : (u ^ 0x80000000u);
}
__device__ __forceinline__ float unordf(unsigned k) {
  unsigned bits = (k & 0x80000000u) ? (k ^ 0x80000000u) : ~k;
  return __uint_as_float(bits);
}
__device__ __forceinline__ unsigned long long packkv(float v, unsigned id) {
  return ((unsigned long long)ordf(v) << 32) | (unsigned long long)(~id);
}
__device__ __forceinline__ float pk_val(unsigned long long e) { return unordf((unsigned)(e >> 32)); }
__device__ __forceinline__ unsigned pk_id(unsigned long long e) { return ~(unsigned)(e & 0xFFFFFFFFu); }

__device__ __forceinline__ unsigned short f2bf(float f) {  // RNE fp32->bf16
  unsigned u = __float_as_uint(f);
  u += 0x7FFFu + ((u >> 16) & 1u);
  return (unsigned short)(u >> 16);
}

// ---- in-LDS bitonic sort, ascending, N power of two ----
template <int N>
__device__ void bitonic_sort(unsigned long long* buf) {
  for (int k = 2; k <= N; k <<= 1) {
    for (int j = k >> 1; j > 0; j >>= 1) {
      for (int e = threadIdx.x; e < N; e += blockDim.x) {
        int p = e ^ j;
        if (p > e) {
          unsigned long long a = buf[e], b = buf[p];
          bool up = ((e & k) == 0);
          if (up ? (a > b) : (a < b)) { buf[e] = b; buf[p] = a; }
        }
      }
      __syncthreads();
    }
  }
}

// =================== P0: Q fp32 -> bf16 (tiny, L2-resident afterwards) ===================
__global__ void p0_qprep(const float* __restrict__ Q, unsigned short* __restrict__ Qp) {
  int e = blockIdx.x * blockDim.x + threadIdx.x;
  if (e < BQ * DQ) Qp[e] = f2bf(Q[e]);
}

// =================== K1: bf16 MFMA GEMM + per-16-item-chunk max ===================
// 512 thr = 8 waves. Tile 256 q x 128 items, full K=128 staged.
// Wave w: q-range (w&3)*64, item-range (w>>2)*64; acc[4][4] of 16x16 C-tiles.
// Xs swizzle: byte ^= slot(x)<<4, slot = ((x>>2)&3)<<1 | (x&1)
//   -> B-frag ds_read_b128 conflict-free (2-way), staging b32 writes ~8-way (16 writes only).
__device__ __forceinline__ unsigned xs_off(int x, int d) {
  unsigned byte = (unsigned)(x * 256 + d * 2);
  unsigned slot = (unsigned)((((x >> 2) & 3) << 1) | (x & 1));
  return byte ^ (slot << 4);
}

__global__ __launch_bounds__(512, 4) void k1_gemm_max(
    const unsigned short* __restrict__ Qp, const float* __restrict__ It,
    float* __restrict__ M) {
  __shared__ unsigned Xs32[8192];   // 32 KB: [128 items][128 d] bf16, swizzled
  __shared__ float Ms[256][8];      // 8 KB: per-(q, chunk) maxima
  const int t = threadIdx.x;
  const int x0 = blockIdx.x * TI;

  // ---- stage It tile (128 d x 128 x fp32) -> bf16 [x][d] swizzled ----
#pragma unroll
  for (int r = 0; r < 4; ++r) {
    int idx = r * 512 + t;          // 0..2047
    int xg = (idx & 31) * 4;        // 0..124
    int d0 = (idx >> 5) * 2;        // 0..126 even
    int xgl = x0 + xg;
    float4 va, vb;
    if (xgl + 3 < XT) {             // XT % 4 == 0: never straddles
      va = *(const float4*)&It[(size_t)d0 * XT + xgl];
      vb = *(const float4*)&It[(size_t)(d0 + 1) * XT + xgl];
    } else {
      va = make_float4(0.f, 0.f, 0.f, 0.f);
      vb = va;
    }
    float fa[4] = {va.x, va.y, va.z, va.w};
    float fb[4] = {vb.x, vb.y, vb.z, vb.w};
#pragma unroll
    for (int j = 0; j < 4; ++j) {
      unsigned pack = (unsigned)f2bf(fa[j]) | ((unsigned)f2bf(fb[j]) << 16);
      Xs32[xs_off(xg + j, d0) >> 2] = pack;
    }
  }
  __syncthreads();

  // ---- MFMA main loop ----
  const int l = t & 63, w = t >> 6;
  const int wq = (w & 3) * 64;      // wave's query base
  const int wi = (w >> 2) * 64;     // wave's item base (within tile)
  const int lm = l & 15, h = l >> 4;

  f32x4 acc[4][4];
#pragma unroll
  for (int a = 0; a < 4; ++a)
#pragma unroll
    for (int b = 0; b < 4; ++b) acc[a][b] = (f32x4){0.f, 0.f, 0.f, 0.f};

#pragma unroll
  for (int n = 0; n < 4; ++n) {     // k-steps of 32
    bf16x8 afr[4];
#pragma unroll
    for (int a = 0; a < 4; ++a) {   // A-frags straight from global (L2-hot 64KB)
      int q = wq + a * 16 + lm;
      afr[a] = *(const bf16x8*)&Qp[(size_t)q * DQ + n * 32 + h * 8];
    }
#pragma unroll
    for (int b = 0; b < 4; ++b) {
      int x = wi + b * 16 + lm;
      bf16x8 bfr = *(const bf16x8*)((const char*)Xs32 + xs_off(x, n * 32 + h * 8));
#pragma unroll
      for (int a = 0; a < 4; ++a)
        acc[a][b] = __builtin_amdgcn_mfma_f32_16x16x32_bf16(afr[a], bfr, acc[a][b], 0, 0, 0);
    }
  }

  // ---- epilogue: per-(q, 16-item-chunk) max ----
  // C layout: col(item) = lane&15, row(q) = (lane>>4)*4 + reg
#pragma unroll
  for (int a = 0; a < 4; ++a)
#pragma unroll
    for (int b = 0; b < 4; ++b) {
      f32x4 v = acc[a][b];
#pragma unroll
      for (int m = 1; m < 16; m <<= 1) {
        v.x = fmaxf(v.x, __shfl_xor(v.x, m));
        v.y = fmaxf(v.y, __shfl_xor(v.y, m));
        v.z = fmaxf(v.z, __shfl_xor(v.z, m));
        v.w = fmaxf(v.w, __shfl_xor(v.w, m));
      }
      if (lm == 0) {
        int qb = wq + a * 16 + h * 4;
        int c = (wi >> 4) + b;
        Ms[qb + 0][c] = v.x;
        Ms[qb + 1][c] = v.y;
        Ms[qb + 2][c] = v.z;
        Ms[qb + 3][c] = v.w;
      }
    }
  __syncthreads();
  {
    int q = t >> 1, half = t & 1;
    int cb = blockIdx.x * 8 + half * 4;
    if (cb + 3 < NCH) {
      float4 v;
      v.x = Ms[q][half * 4 + 0];
      v.y = Ms[q][half * 4 + 1];
      v.z = Ms[q][half * 4 + 2];
      v.w = Ms[q][half * 4 + 3];
      *(float4*)&M[(size_t)q * NCH + cb] = v;
    }
  }
}

// =================== K2: per-query top-100 of (approx) chunk maxima ===================
// Emits <=CAP chunk ids with max >= tau-DELTA (DELTA covers bf16 filter error).
__global__ __launch_bounds__(256) void k2_select(
    const float* __restrict__ M, int* __restrict__ list, int* __restrict__ cnt_out) {
  const int q = blockIdx.x;
  const float4* Mq = (const float4*)(M + (size_t)q * NCH);
  __shared__ unsigned long long buf[SELBUF];
  __shared__ int cnt;
  __shared__ float thr;
  __shared__ int scratch;
  if (threadIdx.x == 0) { cnt = 0; thr = -3.0e38f; }
  __syncthreads();
  const int NF4 = NCH / 4;  // 15625
  for (int base = 0; base < NF4; base += blockDim.x) {
    const int idx = base + threadIdx.x;
    const float t = thr - DELTA;
    if (idx < NF4) {
      float4 v = Mq[idx];
      float vals[4] = {v.x, v.y, v.z, v.w};
#pragma unroll
      for (int j = 0; j < 4; ++j) {
        if (vals[j] >= t) {
          int p = atomicAdd(&cnt, 1);
          if (p < SELBUF) buf[p] = packkv(vals[j], (unsigned)(idx * 4 + j));
        }
      }
    }
    __syncthreads();
    if (cnt > 1024) {  // compact: keep everything within DELTA of the running 100th
      for (int s = cnt + threadIdx.x; s < SELBUF; s += blockDim.x) buf[s] = 0ULL;
      __syncthreads();
      bitonic_sort<SELBUF>(buf);
      float newThr = pk_val(buf[SELBUF - KTOP]);
      if (threadIdx.x == 0) scratch = 0;
      __syncthreads();
      for (int s = threadIdx.x; s < SELBUF; s += blockDim.x)
        if (buf[s] != 0ULL && pk_val(buf[s]) >= newThr - DELTA) atomicAdd(&scratch, 1);
      __syncthreads();
      int keep = scratch;
      if (keep > 1024) keep = 1024;
      for (int s = threadIdx.x; s < keep; s += blockDim.x) buf[s] = buf[SELBUF - keep + s];
      __syncthreads();
      if (threadIdx.x == 0) { cnt = keep; thr = newThr; }
      __syncthreads();
    }
  }
  // final selection + emission
  for (int s = cnt + threadIdx.x; s < SELBUF; s += blockDim.x) buf[s] = 0ULL;
  __syncthreads();
  bitonic_sort<SELBUF>(buf);
  float tau = pk_val(buf[SELBUF - KTOP]);
  if (threadIdx.x == 0) scratch = 0;
  __syncthreads();
  for (int r = threadIdx.x; r < CAP; r += blockDim.x) {
    unsigned long long e = buf[SELBUF - 1 - r];
    if (e != 0ULL && pk_val(e) >= tau - DELTA) {
      list[q * CAP + r] = (int)pk_id(e);
      atomicAdd(&scratch, 1);
    }
  }
  __syncthreads();
  if (threadIdx.x == 0) cnt_out[q] = scratch;
}

// =================== K3: EXACT fp32 rescore of listed chunks (unchanged math) ===================
__global__ __launch_bounds__(256) void k3_rescore(
    const float* __restrict__ Q, const float* __restrict__ It,
    const int* __restrict__ list, const int* __restrict__ cnt_in,
    unsigned long long* __restrict__ cand) {
  const int q = blockIdx.x >> 4;
  const int sg = blockIdx.x & 15;
  __shared__ float qv[DQ];
  if (threadIdx.x < DQ) qv[threadIdx.x] = Q[q * DQ + threadIdx.x];
  __syncthreads();
  const int s = threadIdx.x >> 4;
  const int it = threadIdx.x & 15;
  const int gs = sg * 16 + s;
  unsigned long long out = 0ULL;
  if (gs < cnt_in[q]) {
    const int chunk = list[q * CAP + gs];
    const int x = chunk * CHUNK + it;
    float a = 0.f;
#pragma unroll 8
    for (int d = 0; d < DQ; ++d) a = fmaf(qv[d], It[(size_t)d * XT + x], a);
    out = packkv(a, (unsigned)x);
  }
  cand[(size_t)q * NCAND + gs * CHUNK + it] = out;
}

// =================== K4: final per-query top-100 ===================
__global__ __launch_bounds__(256) void k4_final(
    const unsigned long long* __restrict__ cand, float* __restrict__ out) {
  const int q = blockIdx.x;
  __shared__ unsigned long long buf[NCAND];
  for (int s = threadIdx.x; s < NCAND; s += blockDim.x) buf[s] = cand[(size_t)q * NCAND + s];
  __syncthreads();
  bitonic_sort<NCAND>(buf);
  for (int r = threadIdx.x; r < KTOP; r += blockDim.x) {
    unsigned long long e = buf[NCAND - 1 - r];
    out[q * KTOP + r] = pk_val(e);                       // topk_logits
    out[BQ * KTOP + q * KTOP + r] = (float)pk_id(e);     // topk_item_ids
  }
}

extern "C" void kernel_launch(void* const* d_in, const int* in_sizes, int n_in,
                              void* d_out, int out_size, void* d_ws, size_t ws_size,
                              hipStream_t stream) {
  const float* Q = (const float*)d_in[0];   // [256,128]
  const float* It = (const float*)d_in[1];  // [128,1000000]
  float* out = (float*)d_out;               // [25600 logits][25600 ids]
  char* ws = (char*)d_ws;
  // ws layout: M (64 MB, dead after K2) aliased by cand (8 MB) | list | cnt | Qp
  float* M = (float*)ws;
  unsigned long long* cand = (unsigned long long*)ws;  // alias over dead M
  int* list = (int*)(ws + (size_t)64000000);
  int* cnt = (int*)(ws + (size_t)64000000 + 262144);
  unsigned short* Qp = (unsigned short*)(ws + (size_t)64000000 + 262144 + 1024);

  p0_qprep<<<dim3(128), dim3(256), 0, stream>>>(Q, Qp);
  k1_gemm_max<<<dim3((XT + TI - 1) / TI), dim3(512), 0, stream>>>(Qp, It, M);
  k2_select<<<dim3(BQ), dim3(256), 0, stream>>>(M, list, cnt);
  k3_rescore<<<dim3(BQ * 16), dim3(256), 0, stream>>>(Q, It, list, cnt, cand);
  k4_final<<<dim3(BQ), dim3(256), 0, stream>>>(cand, out);
}